// Round 1
// baseline (699.638 us; speedup 1.0000x reference)
//
#include <hip/hip_runtime.h>

// ---------------- problem constants (match reference) ----------------
#define Zl      384
#define MBr     46
#define NBc     68
#define DEG     7
#define K_INFO  8448
#define N_TX    25344
#define N_LDPC  (NBc * Zl)        // 26112
#define M_CHK   (MBr * Zl)        // 17664
#define E_EDGE  (MBr * DEG * Zl)  // 123648
#define BATCH   128
#define NUM_ITER 20
#define LLR_MAXF 20.0f
#define BCAP    32

// NUMERICS CONTRACT (validated rounds 7-10, absmax 0.0625 vs 0.45):
//  - pure f32 end to end
//  - VN sum: accumulator starts at lch[v], then messages added in
//    ASCENDING edge-id order. DO NOT REORDER (other orders: 1.4-2.0).
//  - CN: two-min with strict < (first-argmin), sign via parity mask.
//  - CN state compression is EXACT (messages are +-min1/+-min2).
// Batch elements are independent -> any batch partitioning is order-safe.
// R12 arithmetic is BIT-IDENTICAL to verified R11 (layout-only change).
//
// PERF MODEL (R9/R10 measured, R12 theory): R11's per-XCD steady working
// set = state+meta 2.8MB + x 1.68MB + lch 1.68MB = 6.2MB > 4MB L2 ->
// reused gather state spills to L3 (~4.5 TB/s) -> ~44us/iter.
// R12 FIX: TEMPORAL BATCH SPLIT. Full 20-iter loop for batch[0:64], then
// batch[64:128]. Per-XCD footprint halves to ~3.1MB < 4MB L2.
// Layout: SECTOR-MAJOR. sector s(0..15) = 8 batch elems = (half h=s>>3,
// XCD g=s&7). Arrays are [16][node][8elem] so each XCD slice is dense
// contiguous -> no 128B-line sharing across XCDs (which would have
// doubled the footprint back). Wave-level gathers become 2KB contiguous
// bursts. Predicted: FETCH_SIZE -> cold-miss-only, total ~500-600us.

// meta bits: [2:0]=amin, [9:3]=nm (neg mask), [10]=stot (parity)
// batch elem b: sector s=b>>3, lane-in-sector b&7 (= ql*4 + channel)

// ---------------------------------------------------------------------
// prep: lch[(s*N_LDPC + 2Z+n)*8 + (b&7)] = -clip(llr[b*N_TX + n])
// ---------------------------------------------------------------------
__global__ void prep_kernel(const float* __restrict__ llr, float* __restrict__ lch) {
    __shared__ float tile[32][33];
    const int n0 = blockIdx.x * 32, b0 = blockIdx.y * 32;
    const int tx = threadIdx.x, ty = threadIdx.y;
#pragma unroll
    for (int j = 0; j < 4; ++j) {
        float v = llr[(b0 + ty + 8 * j) * N_TX + n0 + tx];
        v = fminf(fmaxf(v, -LLR_MAXF), LLR_MAXF);
        tile[ty + 8 * j][tx] = -v;          // [b_local][n_local]
    }
    __syncthreads();
#pragma unroll
    for (int j = 0; j < 4; ++j) {
        const int b = b0 + tx;
        const int n = n0 + ty + 8 * j;
        lch[((size_t)(b >> 3) * N_LDPC + 2 * Zl + n) * 8 + (b & 7)] = tile[tx][ty + 8 * j];
    }
}

// ---------------------------------------------------------------------
// adjacency build, deterministic ascending base-edge order.
// badj[c*BCAP + slot] = sh | (d<<10) | (r<<13)   (sh<512, d<8, r<64)
// cadj[r*DEG + d]     = sh | (c<<10)             (cn-side, no col gather)
// ---------------------------------------------------------------------
__global__ void base_build_kernel(const int* __restrict__ col,
                                  int* __restrict__ bcount, int* __restrict__ badj,
                                  int* __restrict__ cadj) {
    __shared__ int sc[MBr * DEG];
    __shared__ int ssh[MBr * DEG];
    const int t = threadIdx.x;
    if (t < MBr * DEG) {
        const int v0 = col[t * Zl];         // col[be*Z] = c*Z + shift
        const int c  = v0 / Zl;
        sc[t]  = c;
        ssh[t] = v0 - c * Zl;
        cadj[t] = ssh[t] | (sc[t] << 10);
    }
    if (t < NBc) bcount[t] = 0;
    __syncthreads();
    if (t < MBr * DEG) {
        const int c = sc[t];
        int slot = 0;
        for (int u = 0; u < t; ++u) slot += (sc[u] == c) ? 1 : 0;
        const int r = t / DEG, d = t - r * DEG;
        if (slot < BCAP) badj[c * BCAP + slot] = ssh[t] | (d << 10) | (r << 13);
        atomicAdd(&bcount[c], 1);           // order-independent (count only)
    }
}

// ---------------------------------------------------------------------
// CN update. blockIdx%8 = XCD group g; sector s = h*8+g. 128 nodes/blk,
// 2 lanes per node (ql = quad within sector), float4 quad per lane.
// state: [16][M_CHK][16 floats] = per (s,cn): {m1,m2}x4ch x 2 quads
// meta : [16][M_CHK][8 ushort]
// ---------------------------------------------------------------------
template <bool FIRST>
__global__ void cn_kernel(const float* __restrict__ x,
                          float* __restrict__ state_f2,
                          unsigned short* __restrict__ meta,
                          const int* __restrict__ cadj, const int h) {
    const int qg   = blockIdx.x & 7;          // XCD group
    const int tile = blockIdx.x >> 3;
    const int nl   = threadIdx.x >> 1;        // node within tile (0..127)
    const int ql   = threadIdx.x & 1;         // quad within sector
    const int s    = h * 8 + qg;              // sector
    const int cn   = tile * 128 + nl;         // 128 | Z -> single r per tile
    const int r    = cn / Zl;
    const int i    = cn - r * Zl;

    const float4* xp = (const float4*)x + (size_t)s * N_LDPC * 2;
    float4* sp = (float4*)state_f2 + ((size_t)s * M_CHK + cn) * 4 + ql * 2;
    ushort4* mp = (ushort4*)meta + ((size_t)s * M_CHK + cn) * 2 + ql;

    float omin1[4], omin2[4];
    int oamin[4]; unsigned onm[4], ostot[4];
    if (!FIRST) {
        const float4 sA = sp[0];
        const float4 sB = sp[1];
        omin1[0] = sA.x; omin2[0] = sA.y; omin1[1] = sA.z; omin2[1] = sA.w;
        omin1[2] = sB.x; omin2[2] = sB.y; omin1[3] = sB.z; omin2[3] = sB.w;
        const ushort4 mt = mp[0];
        const unsigned m4[4] = {mt.x, mt.y, mt.z, mt.w};
#pragma unroll
        for (int c = 0; c < 4; ++c) {
            oamin[c] = m4[c] & 7u;
            onm[c]   = (m4[c] >> 3) & 0x7Fu;
            ostot[c] = (m4[c] >> 10) & 1u;
        }
    }

    float min1[4] = {1e30f, 1e30f, 1e30f, 1e30f};
    float min2[4] = {1e30f, 1e30f, 1e30f, 1e30f};
    int   amin[4] = {0, 0, 0, 0};
    unsigned nm[4] = {0u, 0u, 0u, 0u};

#pragma unroll
    for (int d = 0; d < DEG; ++d) {
        const int pk = cadj[r * DEG + d];
        const int sh = pk & 0x3FF;
        const int c  = pk >> 10;
        int ii = i + sh; if (ii >= Zl) ii -= Zl;
        const int v = c * Zl + ii;
        const float4 xv = xp[(size_t)v * 2 + ql];
        float t[4] = {xv.x, xv.y, xv.z, xv.w};
        if (!FIRST) {
#pragma unroll
            for (int c2 = 0; c2 < 4; ++c2) {
                const float omag = (d == oamin[c2]) ? omin2[c2] : omin1[c2];
                const float mold = (ostot[c2] ^ ((onm[c2] >> d) & 1u)) ? -omag : omag;
                t[c2] -= mold;
            }
        }
#pragma unroll
        for (int c2 = 0; c2 < 4; ++c2) {
            const float mag = fabsf(t[c2]);
            nm[c2] |= (t[c2] < 0.f ? 1u : 0u) << d;
            if (mag < min1[c2]) { min2[c2] = min1[c2]; min1[c2] = mag; amin[c2] = d; }
            else if (mag < min2[c2]) { min2[c2] = mag; }
        }
    }

    float4 oA, oB;
    oA.x = min1[0]; oA.y = min2[0]; oA.z = min1[1]; oA.w = min2[1];
    oB.x = min1[2]; oB.y = min2[2]; oB.z = min1[3]; oB.w = min2[3];
    sp[0] = oA;
    sp[1] = oB;
    ushort4 mo;
    unsigned mv[4];
#pragma unroll
    for (int c = 0; c < 4; ++c)
        mv[c] = (unsigned)amin[c] | (nm[c] << 3) | ((unsigned)(__popc(nm[c]) & 1) << 10);
    mo.x = (unsigned short)mv[0]; mo.y = (unsigned short)mv[1];
    mo.z = (unsigned short)mv[2]; mo.w = (unsigned short)mv[3];
    mp[0] = mo;
}

// ---------------------------------------------------------------------
// VN update (LCH-FIRST). Same sector mapping as cn_kernel.
// x[v] = lch[v]; then += reconstructed m_cv[e], ascending base-edge id.
// ---------------------------------------------------------------------
__global__ void vn_kernel(const float* __restrict__ lch,
                          const float* __restrict__ state_f2,
                          const unsigned short* __restrict__ meta,
                          const int* __restrict__ bcount, const int* __restrict__ badj,
                          float* __restrict__ x, const int h) {
    const int qg   = blockIdx.x & 7;
    const int tile = blockIdx.x >> 3;
    const int nl   = threadIdx.x >> 1;
    const int ql   = threadIdx.x & 1;
    const int s    = h * 8 + qg;
    const int v    = tile * 128 + nl;         // 128 | Z -> single c per tile
    const int c    = v / Zl;
    const int j    = v - c * Zl;
    const int cnt  = min(bcount[c], BCAP);
    const int* bp  = badj + c * BCAP;
    const float4* stp = (const float4*)state_f2 + (size_t)s * M_CHK * 4;
    const ushort4* mtp = (const ushort4*)meta + (size_t)s * M_CHK * 2;

    float4 sacc = ((const float4*)lch)[((size_t)s * N_LDPC + v) * 2 + ql];  // lch FIRST
    for (int k = 0; k < cnt; ++k) {
        const int pk = bp[k];
        const int sh = pk & 0x3FF;
        const int d  = (pk >> 10) & 7;
        const int r  = pk >> 13;
        int i = j - sh;
        if (i < 0) i += Zl;
        const int cnb = r * Zl + i;
        const float4 sA = stp[(size_t)cnb * 4 + ql * 2];
        const float4 sB = stp[(size_t)cnb * 4 + ql * 2 + 1];
        const ushort4 mt = mtp[(size_t)cnb * 2 + ql];
        const unsigned m4[4] = {mt.x, mt.y, mt.z, mt.w};
        const float mn1[4] = {sA.x, sA.z, sB.x, sB.z};
        const float mn2[4] = {sA.y, sA.w, sB.y, sB.w};
        float val[4];
#pragma unroll
        for (int cc = 0; cc < 4; ++cc) {
            const int   am  = m4[cc] & 7u;
            const unsigned nmv = (m4[cc] >> 3) & 0x7Fu;
            const unsigned st  = (m4[cc] >> 10) & 1u;
            const float mag = (d == am) ? mn2[cc] : mn1[cc];
            val[cc] = (st ^ ((nmv >> d) & 1u)) ? -mag : mag;
        }
        sacc.x += val[0]; sacc.y += val[1]; sacc.z += val[2]; sacc.w += val[3];
    }
    ((float4*)x)[((size_t)s * N_LDPC + v) * 2 + ql] = sacc;
}

// ---------------------------------------------------------------------
// output: out[b*K + k] = -x[(s*N_LDPC + k)*8 + (b&7)], k < K_INFO
// ---------------------------------------------------------------------
__global__ void out_kernel(const float* __restrict__ x, float* __restrict__ out) {
    __shared__ float tile[32][33];
    const int k0 = blockIdx.x * 32, b0 = blockIdx.y * 32;
    const int tx = threadIdx.x, ty = threadIdx.y;
#pragma unroll
    for (int j = 0; j < 4; ++j) {
        const int b = b0 + tx;
        const int k = k0 + ty + 8 * j;
        tile[ty + 8 * j][tx] = -x[((size_t)(b >> 3) * N_LDPC + k) * 8 + (b & 7)];
    }
    __syncthreads();
#pragma unroll
    for (int j = 0; j < 4; ++j) {
        out[(b0 + ty + 8 * j) * K_INFO + k0 + tx] = tile[tx][ty + 8 * j];
    }
}

// ---------------------------------------------------------------------
extern "C" void kernel_launch(void* const* d_in, const int* in_sizes, int n_in,
                              void* d_out, int out_size, void* d_ws, size_t ws_size,
                              hipStream_t stream) {
    const float* llr = (const float*)d_in[0];
    // d_in[1] = row (unused: row index derivable from edge-id structure)
    const int* col = (const int*)d_in[2];
    float* out = (float*)d_out;

    char* ws = (char*)d_ws;
    float* lch   = (float*)ws;                                   // 13,369,344 B
    float* x     = lch + (size_t)N_LDPC * BATCH;                 // 13,369,344 B
    float* state = x + (size_t)N_LDPC * BATCH;                   // 18,087,936 B
    unsigned short* meta = (unsigned short*)(state + (size_t)M_CHK * BATCH * 2); // 4,521,984 B
    int* bcount = (int*)(meta + (size_t)M_CHK * BATCH);          // 68*4
    int* badj   = bcount + NBc;                                  // 68*32*4
    int* cadj   = badj + NBc * BCAP;                             // 322*4
    // total ~49.4 MB

    // zero full lch: covers the punctured 2Z region in every sector
    hipMemsetAsync(lch, 0, (size_t)N_LDPC * BATCH * sizeof(float), stream);
    prep_kernel<<<dim3(N_TX / 32, BATCH / 32), dim3(32, 8), 0, stream>>>(llr, lch);

    base_build_kernel<<<1, 512, 0, stream>>>(col, bcount, badj, cadj);

    // grids: (node_tiles of 128) x 8 XCD groups; blockIdx%8 -> XCD
    const int cn_grid = (M_CHK / 128) * 8;    // 138*8 = 1104
    const int vn_grid = (N_LDPC / 128) * 8;   // 204*8 = 1632

    // TEMPORAL BATCH SPLIT: full iteration loop per half -> per-XCD
    // working set (state+meta 1.41 + x 0.84 + lch 0.84 MB) fits 4MB L2.
    for (int h = 0; h < 2; ++h) {
        // iteration 1: vn_sum == lch exactly (m_cv == 0)
        cn_kernel<true><<<cn_grid, 256, 0, stream>>>(lch, state, meta, cadj, h);
        vn_kernel<<<vn_grid, 256, 0, stream>>>(lch, state, meta, bcount, badj, x, h);
        for (int t = 1; t < NUM_ITER; ++t) {
            cn_kernel<false><<<cn_grid, 256, 0, stream>>>(x, state, meta, cadj, h);
            vn_kernel<<<vn_grid, 256, 0, stream>>>(lch, state, meta, bcount, badj, x, h);
        }
    }

    out_kernel<<<dim3(K_INFO / 32, BATCH / 32), dim3(32, 8), 0, stream>>>(x, out);
}